// Round 1
// baseline (329.707 us; speedup 1.0000x reference)
//
#include <hip/hip_runtime.h>
#include <hip/hip_bf16.h>

// Problem constants
#define TSEQ 2048
#define CDIM 768
#define NHEAD 12
#define DHEAD 64
#define FDIM 3072
#define MROWS 4096   // B*T
#define BH 24        // B*H

typedef __attribute__((ext_vector_type(8))) short short8;
typedef __attribute__((ext_vector_type(4))) float f32x4;

__device__ inline unsigned short f2bf(float f) {
  __hip_bfloat16 h = __float2bfloat16(f);
  return __builtin_bit_cast(unsigned short, h);
}

// ---------------- LayerNorm: fp32 in -> bf16 out ----------------
__global__ __launch_bounds__(256) void ln_kernel(
    const float* __restrict__ x, const float* __restrict__ g,
    const float* __restrict__ b, unsigned short* __restrict__ out) {
  int row = blockIdx.x;
  int tid = threadIdx.x;
  const float* xr = x + (size_t)row * CDIM;
  float v[3];
  float s = 0.f;
#pragma unroll
  for (int i = 0; i < 3; ++i) { v[i] = xr[tid + i * 256]; s += v[i]; }
#pragma unroll
  for (int m = 1; m < 64; m <<= 1) s += __shfl_xor(s, m);
  __shared__ float red[8];
  int w = tid >> 6;
  if ((tid & 63) == 0) red[w] = s;
  __syncthreads();
  float mean = (red[0] + red[1] + red[2] + red[3]) * (1.f / CDIM);
  float vs = 0.f;
#pragma unroll
  for (int i = 0; i < 3; ++i) { float d = v[i] - mean; vs += d * d; }
#pragma unroll
  for (int m = 1; m < 64; m <<= 1) vs += __shfl_xor(vs, m);
  if ((tid & 63) == 0) red[4 + w] = vs;
  __syncthreads();
  float var = (red[4] + red[5] + red[6] + red[7]) * (1.f / CDIM);
  float rstd = rsqrtf(var + 1e-5f);
  unsigned short* orow = out + (size_t)row * CDIM;
#pragma unroll
  for (int i = 0; i < 3; ++i) {
    int c = tid + i * 256;
    orow[c] = f2bf((v[i] - mean) * rstd * g[c] + b[c]);
  }
}

// ------------- generic fp32 [R][C] -> bf16 [C][R] transpose pack -------------
__global__ __launch_bounds__(256) void transpose_pack(
    const float* __restrict__ in, unsigned short* __restrict__ out, int R, int C) {
  __shared__ float tile[32][33];
  int c0 = blockIdx.x * 32, r0 = blockIdx.y * 32;
  int x = threadIdx.x & 31, y = threadIdx.x >> 5;
#pragma unroll
  for (int i = 0; i < 4; ++i)
    tile[y + i * 8][x] = in[(size_t)(r0 + y + i * 8) * C + c0 + x];
  __syncthreads();
#pragma unroll
  for (int i = 0; i < 4; ++i)
    out[(size_t)(c0 + y + i * 8) * R + r0 + x] = f2bf(tile[x][y + i * 8]);
}

// ------------- QKV weight pack: Wq/Wk/Wv [H][C][D] fp32 -> bf16 [2304][768] (n-major, k=c) -------------
__global__ __launch_bounds__(256) void qkv_pack(
    const float* __restrict__ Wq, const float* __restrict__ Wk,
    const float* __restrict__ Wv, unsigned short* __restrict__ out) {
  __shared__ float tile[32][33];
  int ph = blockIdx.z;
  int proj = ph / NHEAD, h = ph % NHEAD;
  const float* in = (proj == 0 ? Wq : (proj == 1 ? Wk : Wv)) + (size_t)h * CDIM * DHEAD;
  int c0 = blockIdx.x * 32, d0 = blockIdx.y * 32;
  int x = threadIdx.x & 31, y = threadIdx.x >> 5;
#pragma unroll
  for (int i = 0; i < 4; ++i)
    tile[y + i * 8][x] = in[(size_t)(c0 + y + i * 8) * DHEAD + d0 + x];
  __syncthreads();
#pragma unroll
  for (int i = 0; i < 4; ++i)
    out[(size_t)(proj * CDIM + h * DHEAD + d0 + y + i * 8) * CDIM + c0 + x] =
        f2bf(tile[x][y + i * 8]);
}

// ------------- V [bh][T][D] bf16 -> VT [bh][D][T] bf16 -------------
__global__ __launch_bounds__(256) void vtrans(
    const unsigned short* __restrict__ V, unsigned short* __restrict__ VT) {
  __shared__ unsigned short tile[32][33];
  int bh = blockIdx.z;
  int t0 = blockIdx.x * 32, d0 = blockIdx.y * 32;
  int x = threadIdx.x & 31, y = threadIdx.x >> 5;
  const unsigned short* in = V + (size_t)bh * TSEQ * DHEAD;
  unsigned short* out = VT + (size_t)bh * DHEAD * TSEQ;
#pragma unroll
  for (int i = 0; i < 4; ++i)
    tile[y + i * 8][x] = in[(size_t)(t0 + y + i * 8) * DHEAD + d0 + x];
  __syncthreads();
#pragma unroll
  for (int i = 0; i < 4; ++i)
    out[(size_t)(d0 + y + i * 8) * TSEQ + t0 + x] = tile[x][y + i * 8];
}

// ------------- bf16 MFMA GEMM, A [M][K], BT [N][K], 128x128 tile, BK=64 -------------
// EPI 0: scatter QKV (outb unused; qo/ko/vo [bh][T][D] bf16)
// EPI 1: outf = acc + bias + aux            (fp32)   [proj + residual]
// EPI 2: outb = relu(acc + bias)            (bf16)   [FF1]
// EPI 3: outf = aux + relu(acc + bias)      (fp32)   [FF2 + residual]
template <int EPI>
__global__ __launch_bounds__(256) void gemm_bt(
    const unsigned short* __restrict__ A, const unsigned short* __restrict__ BT,
    int M, int N, int K,
    const float* __restrict__ bias, const float* __restrict__ aux,
    float* __restrict__ outf, unsigned short* __restrict__ outb,
    unsigned short* __restrict__ qo, unsigned short* __restrict__ ko,
    unsigned short* __restrict__ vo) {
  __shared__ unsigned short As[128 * 64];
  __shared__ unsigned short Bs[128 * 64];
  int tid = threadIdx.x;
  int lane = tid & 63, wave = tid >> 6;
  int wr = wave >> 1, wc = wave & 1;
  int l15 = lane & 15, lg = lane >> 4;
  size_t bm = (size_t)blockIdx.x * 128, bn = (size_t)blockIdx.y * 128;
  f32x4 acc[4][4] = {};
  for (int kt = 0; kt < K; kt += 64) {
#pragma unroll
    for (int i = 0; i < 4; ++i) {
      int c = tid + i * 256;
      int row = c >> 3, cc = c & 7;
      int4 va = *reinterpret_cast<const int4*>(A + (bm + row) * K + kt + cc * 8);
      *reinterpret_cast<int4*>(&As[row * 64 + ((cc * 8) ^ ((row & 7) << 3))]) = va;
      int4 vb = *reinterpret_cast<const int4*>(BT + (bn + row) * K + kt + cc * 8);
      *reinterpret_cast<int4*>(&Bs[row * 64 + ((cc * 8) ^ ((row & 7) << 3))]) = vb;
    }
    __syncthreads();
#pragma unroll
    for (int kk = 0; kk < 64; kk += 32) {
      int kb = kk + lg * 8;
      short8 af[4], bfr[4];
#pragma unroll
      for (int m = 0; m < 4; ++m) {
        int row = wr * 64 + m * 16 + l15;
        af[m] = *reinterpret_cast<const short8*>(&As[row * 64 + (kb ^ ((row & 7) << 3))]);
      }
#pragma unroll
      for (int n = 0; n < 4; ++n) {
        int row = wc * 64 + n * 16 + l15;
        bfr[n] = *reinterpret_cast<const short8*>(&Bs[row * 64 + (kb ^ ((row & 7) << 3))]);
      }
#pragma unroll
      for (int m = 0; m < 4; ++m)
#pragma unroll
        for (int n = 0; n < 4; ++n)
          acc[m][n] = __builtin_amdgcn_mfma_f32_16x16x32_bf16(af[m], bfr[n], acc[m][n], 0, 0, 0);
    }
    __syncthreads();
  }
#pragma unroll
  for (int m = 0; m < 4; ++m) {
#pragma unroll
    for (int n = 0; n < 4; ++n) {
#pragma unroll
      for (int r = 0; r < 4; ++r) {
        int row = (int)bm + wr * 64 + m * 16 + lg * 4 + r;
        int col = (int)bn + wc * 64 + n * 16 + l15;
        float val = acc[m][n][r];
        if constexpr (EPI == 0) {
          int proj = col / CDIM, rem = col % CDIM;
          int h = rem >> 6, d = rem & 63;
          int b = row >> 11, t = row & (TSEQ - 1);
          size_t idx = (((size_t)(b * NHEAD + h)) * TSEQ + t) * DHEAD + d;
          unsigned short bv = f2bf(val);
          if (proj == 0) qo[idx] = bv;
          else if (proj == 1) ko[idx] = bv;
          else vo[idx] = bv;
        } else if constexpr (EPI == 1) {
          size_t idx = (size_t)row * CDIM + col;
          outf[idx] = val + bias[col] + aux[idx];
        } else if constexpr (EPI == 2) {
          size_t idx = (size_t)row * FDIM + col;
          outb[idx] = f2bf(fmaxf(val + bias[col], 0.f));
        } else {
          size_t idx = (size_t)row * CDIM + col;
          outf[idx] = aux[idx] + fmaxf(val + bias[col], 0.f);
        }
      }
    }
  }
}

// ------------- causal flash attention: 1 wave = 16 q rows, KV tile = 32 -------------
__global__ __launch_bounds__(256) void attn_kernel(
    const unsigned short* __restrict__ Q, const unsigned short* __restrict__ Kd,
    const unsigned short* __restrict__ VT, unsigned short* __restrict__ O) {
  __shared__ unsigned short plds[4][16 * 40];  // per-wave P buffer, 80B pitch (16B aligned)
  int wave = threadIdx.x >> 6, lane = threadIdx.x & 63;
  int gw = blockIdx.x * 4 + wave;   // 0..3071
  int qt = gw & 127, bh = gw >> 7;  // 128 q-tiles per (b,h)
  int qbase = qt * 16;
  int l15 = lane & 15, lg = lane >> 4;
  const unsigned short* qp = Q + (size_t)bh * TSEQ * DHEAD;
  const unsigned short* kp = Kd + (size_t)bh * TSEQ * DHEAD;
  const unsigned short* vp = VT + (size_t)bh * DHEAD * TSEQ;
  unsigned short* pw = plds[wave];

  short8 qf[2];
#pragma unroll
  for (int kk = 0; kk < 2; ++kk)
    qf[kk] = *reinterpret_cast<const short8*>(qp + (size_t)(qbase + l15) * DHEAD + kk * 32 + lg * 8);

  f32x4 o_acc[4] = {};
  float mrun[4], lrun[4];
#pragma unroll
  for (int r = 0; r < 4; ++r) { mrun[r] = -1e30f; lrun[r] = 0.f; }
  const float sc = 0.03608439182435161f;  // 768^-0.5
  const float L2E = 1.4426950408889634f;

  for (int s0 = 0; s0 < qbase + 16; s0 += 32) {
    f32x4 sacc[2] = {};
#pragma unroll
    for (int st = 0; st < 2; ++st) {
#pragma unroll
      for (int kk = 0; kk < 2; ++kk) {
        short8 kf = *reinterpret_cast<const short8*>(
            kp + (size_t)(s0 + st * 16 + l15) * DHEAD + kk * 32 + lg * 8);
        sacc[st] = __builtin_amdgcn_mfma_f32_16x16x32_bf16(qf[kk], kf, sacc[st], 0, 0, 0);
      }
    }
#pragma unroll
    for (int r = 0; r < 4; ++r) {
      int qrow = qbase + lg * 4 + r;
      float v0 = sacc[0][r] * sc;
      float v1 = sacc[1][r] * sc;
      if (s0 + l15 > qrow) v0 = -1e30f;
      if (s0 + 16 + l15 > qrow) v1 = -1e30f;
      float mr = fmaxf(v0, v1);
#pragma unroll
      for (int msk = 1; msk < 16; msk <<= 1) mr = fmaxf(mr, __shfl_xor(mr, msk));
      float mnew = fmaxf(mrun[r], mr);
      float alpha = exp2f((mrun[r] - mnew) * L2E);
      float p0 = exp2f((v0 - mnew) * L2E);
      float p1 = exp2f((v1 - mnew) * L2E);
      float rs = p0 + p1;
#pragma unroll
      for (int msk = 1; msk < 16; msk <<= 1) rs += __shfl_xor(rs, msk);
      lrun[r] = lrun[r] * alpha + rs;
      mrun[r] = mnew;
#pragma unroll
      for (int n = 0; n < 4; ++n) o_acc[n][r] *= alpha;
      pw[(lg * 4 + r) * 40 + l15] = f2bf(p0);
      pw[(lg * 4 + r) * 40 + 16 + l15] = f2bf(p1);
    }
    // same-wave LDS write->read: DS ops execute in order per wave
    short8 pa = *reinterpret_cast<const short8*>(pw + l15 * 40 + lg * 8);
#pragma unroll
    for (int n = 0; n < 4; ++n) {
      short8 vf = *reinterpret_cast<const short8*>(
          vp + (size_t)(n * 16 + l15) * TSEQ + s0 + lg * 8);
      o_acc[n] = __builtin_amdgcn_mfma_f32_16x16x32_bf16(pa, vf, o_acc[n], 0, 0, 0);
    }
  }
  int b = bh / NHEAD, h = bh % NHEAD;
#pragma unroll
  for (int r = 0; r < 4; ++r) {
    float inv = 1.f / lrun[r];
    int row = qbase + lg * 4 + r;
#pragma unroll
    for (int n = 0; n < 4; ++n)
      O[(size_t)(b * TSEQ + row) * CDIM + h * DHEAD + n * 16 + l15] = f2bf(o_acc[n][r] * inv);
  }
}

extern "C" void kernel_launch(void* const* d_in, const int* in_sizes, int n_in,
                              void* d_out, int out_size, void* d_ws, size_t ws_size,
                              hipStream_t stream) {
  const float* x    = (const float*)d_in[0];
  const float* Wq   = (const float*)d_in[1];
  const float* Wk   = (const float*)d_in[2];
  const float* Wv   = (const float*)d_in[3];
  const float* Wp   = (const float*)d_in[4];
  const float* bp   = (const float*)d_in[5];
  const float* W1   = (const float*)d_in[6];
  const float* b1   = (const float*)d_in[7];
  const float* W2   = (const float*)d_in[8];
  const float* b2   = (const float*)d_in[9];
  const float* ln1g = (const float*)d_in[10];
  const float* ln1b = (const float*)d_in[11];
  const float* ln2g = (const float*)d_in[12];
  const float* ln2b = (const float*)d_in[13];
  float* out = (float*)d_out;

  char* ws = (char*)d_ws;
  auto alloc = [&](size_t bytes) {
    char* p = ws;
    ws += (bytes + 255) & ~(size_t)255;
    return p;
  };
  unsigned short* h1    = (unsigned short*)alloc((size_t)MROWS * CDIM * 2);
  unsigned short* WqkvT = (unsigned short*)alloc((size_t)3 * CDIM * CDIM * 2);
  unsigned short* WpT   = (unsigned short*)alloc((size_t)CDIM * CDIM * 2);
  unsigned short* W1T   = (unsigned short*)alloc((size_t)FDIM * CDIM * 2);
  unsigned short* W2T   = (unsigned short*)alloc((size_t)CDIM * FDIM * 2);
  unsigned short* Qb    = (unsigned short*)alloc((size_t)BH * TSEQ * DHEAD * 2);
  unsigned short* Kb    = (unsigned short*)alloc((size_t)BH * TSEQ * DHEAD * 2);
  unsigned short* Vb    = (unsigned short*)alloc((size_t)BH * TSEQ * DHEAD * 2);
  unsigned short* VTb   = (unsigned short*)alloc((size_t)BH * TSEQ * DHEAD * 2);
  unsigned short* AO    = (unsigned short*)alloc((size_t)MROWS * CDIM * 2);
  float*          x1    = (float*)alloc((size_t)MROWS * CDIM * 4);
  unsigned short* h2    = (unsigned short*)alloc((size_t)MROWS * CDIM * 2);
  unsigned short* a1    = (unsigned short*)alloc((size_t)MROWS * FDIM * 2);

  // weight packs (bf16, B^T layout)
  qkv_pack<<<dim3(24, 2, 36), 256, 0, stream>>>(Wq, Wk, Wv, WqkvT);
  transpose_pack<<<dim3(24, 24), 256, 0, stream>>>(Wp, WpT, CDIM, CDIM);
  transpose_pack<<<dim3(96, 24), 256, 0, stream>>>(W1, W1T, CDIM, FDIM);
  transpose_pack<<<dim3(24, 96), 256, 0, stream>>>(W2, W2T, FDIM, CDIM);

  // LN1 -> h1
  ln_kernel<<<4096, 256, 0, stream>>>(x, ln1g, ln1b, h1);
  // QKV projection
  gemm_bt<0><<<dim3(32, 18), 256, 0, stream>>>(h1, WqkvT, MROWS, 3 * CDIM, CDIM,
                                               nullptr, nullptr, nullptr, nullptr, Qb, Kb, Vb);
  // V -> V^T
  vtrans<<<dim3(64, 2, BH), 256, 0, stream>>>(Vb, VTb);
  // attention
  attn_kernel<<<768, 256, 0, stream>>>(Qb, Kb, VTb, AO);
  // output projection + residual -> x1 (fp32)
  gemm_bt<1><<<dim3(32, 6), 256, 0, stream>>>(AO, WpT, MROWS, CDIM, CDIM,
                                              bp, x, x1, nullptr, nullptr, nullptr, nullptr);
  // LN2 -> h2
  ln_kernel<<<4096, 256, 0, stream>>>(x1, ln2g, ln2b, h2);
  // FF1 (+ReLU) -> a1 bf16
  gemm_bt<2><<<dim3(32, 24), 256, 0, stream>>>(h2, W1T, MROWS, FDIM, CDIM,
                                               b1, nullptr, nullptr, a1, nullptr, nullptr, nullptr);
  // FF2 (+ReLU) + residual -> out fp32
  gemm_bt<3><<<dim3(32, 6), 256, 0, stream>>>(a1, W2T, MROWS, CDIM, FDIM,
                                              b2, x1, out, nullptr, nullptr, nullptr, nullptr);
}

// Round 2
// 279.675 us; speedup vs baseline: 1.1789x; 1.1789x over previous
//
#include <hip/hip_runtime.h>
#include <hip/hip_bf16.h>

// Problem constants
#define TSEQ 2048
#define CDIM 768
#define NHEAD 12
#define DHEAD 64
#define FDIM 3072
#define MROWS 4096   // B*T
#define BH 24        // B*H

typedef __attribute__((ext_vector_type(8))) short short8;
typedef __attribute__((ext_vector_type(4))) float f32x4;

__device__ inline unsigned short f2bf(float f) {
  __hip_bfloat16 h = __float2bfloat16(f);
  return __builtin_bit_cast(unsigned short, h);
}

// ---------------- LayerNorm: fp32 in -> bf16 out ----------------
__global__ __launch_bounds__(256) void ln_kernel(
    const float* __restrict__ x, const float* __restrict__ g,
    const float* __restrict__ b, unsigned short* __restrict__ out) {
  int row = blockIdx.x;
  int tid = threadIdx.x;
  const float* xr = x + (size_t)row * CDIM;
  float v[3];
  float s = 0.f;
#pragma unroll
  for (int i = 0; i < 3; ++i) { v[i] = xr[tid + i * 256]; s += v[i]; }
#pragma unroll
  for (int m = 1; m < 64; m <<= 1) s += __shfl_xor(s, m);
  __shared__ float red[8];
  int w = tid >> 6;
  if ((tid & 63) == 0) red[w] = s;
  __syncthreads();
  float mean = (red[0] + red[1] + red[2] + red[3]) * (1.f / CDIM);
  float vs = 0.f;
#pragma unroll
  for (int i = 0; i < 3; ++i) { float d = v[i] - mean; vs += d * d; }
#pragma unroll
  for (int m = 1; m < 64; m <<= 1) vs += __shfl_xor(vs, m);
  if ((tid & 63) == 0) red[4 + w] = vs;
  __syncthreads();
  float var = (red[4] + red[5] + red[6] + red[7]) * (1.f / CDIM);
  float rstd = rsqrtf(var + 1e-5f);
  unsigned short* orow = out + (size_t)row * CDIM;
#pragma unroll
  for (int i = 0; i < 3; ++i) {
    int c = tid + i * 256;
    orow[c] = f2bf((v[i] - mean) * rstd * g[c] + b[c]);
  }
}

// ------------- generic fp32 [R][C] -> bf16 [C][R] transpose pack -------------
__global__ __launch_bounds__(256) void transpose_pack(
    const float* __restrict__ in, unsigned short* __restrict__ out, int R, int C) {
  __shared__ float tile[32][33];
  int c0 = blockIdx.x * 32, r0 = blockIdx.y * 32;
  int x = threadIdx.x & 31, y = threadIdx.x >> 5;
#pragma unroll
  for (int i = 0; i < 4; ++i)
    tile[y + i * 8][x] = in[(size_t)(r0 + y + i * 8) * C + c0 + x];
  __syncthreads();
#pragma unroll
  for (int i = 0; i < 4; ++i)
    out[(size_t)(c0 + y + i * 8) * R + r0 + x] = f2bf(tile[x][y + i * 8]);
}

// ------------- QKV weight pack: Wq/Wk/Wv [H][C][D] fp32 -> bf16 [2304][768] (n-major, k=c) -------------
__global__ __launch_bounds__(256) void qkv_pack(
    const float* __restrict__ Wq, const float* __restrict__ Wk,
    const float* __restrict__ Wv, unsigned short* __restrict__ out) {
  __shared__ float tile[32][33];
  int ph = blockIdx.z;
  int proj = ph / NHEAD, h = ph % NHEAD;
  const float* in = (proj == 0 ? Wq : (proj == 1 ? Wk : Wv)) + (size_t)h * CDIM * DHEAD;
  int c0 = blockIdx.x * 32, d0 = blockIdx.y * 32;
  int x = threadIdx.x & 31, y = threadIdx.x >> 5;
#pragma unroll
  for (int i = 0; i < 4; ++i)
    tile[y + i * 8][x] = in[(size_t)(c0 + y + i * 8) * DHEAD + d0 + x];
  __syncthreads();
#pragma unroll
  for (int i = 0; i < 4; ++i)
    out[(size_t)(proj * CDIM + h * DHEAD + d0 + y + i * 8) * CDIM + c0 + x] =
        f2bf(tile[x][y + i * 8]);
}

// ------------- V [bh][T][D] bf16 -> VT [bh][D][T] bf16 -------------
__global__ __launch_bounds__(256) void vtrans(
    const unsigned short* __restrict__ V, unsigned short* __restrict__ VT) {
  __shared__ unsigned short tile[32][33];
  int bh = blockIdx.z;
  int t0 = blockIdx.x * 32, d0 = blockIdx.y * 32;
  int x = threadIdx.x & 31, y = threadIdx.x >> 5;
  const unsigned short* in = V + (size_t)bh * TSEQ * DHEAD;
  unsigned short* out = VT + (size_t)bh * DHEAD * TSEQ;
#pragma unroll
  for (int i = 0; i < 4; ++i)
    tile[y + i * 8][x] = in[(size_t)(t0 + y + i * 8) * DHEAD + d0 + x];
  __syncthreads();
#pragma unroll
  for (int i = 0; i < 4; ++i)
    out[(size_t)(d0 + y + i * 8) * TSEQ + t0 + x] = tile[x][y + i * 8];
}

// ------------- bf16 MFMA GEMM, A [M][K], BT [N][K], 128x128 tile, BK=64 -------------
// EPI 0: scatter QKV (outb unused; qo/ko/vo [bh][T][D] bf16)
// EPI 1: outf = acc + bias + aux            (fp32)   [proj + residual]
// EPI 2: outb = relu(acc + bias)            (bf16)   [FF1]
// EPI 3: outf = aux + relu(acc + bias)      (fp32)   [FF2 + residual]
template <int EPI>
__global__ __launch_bounds__(256) void gemm_bt(
    const unsigned short* __restrict__ A, const unsigned short* __restrict__ BT,
    int M, int N, int K,
    const float* __restrict__ bias, const float* __restrict__ aux,
    float* __restrict__ outf, unsigned short* __restrict__ outb,
    unsigned short* __restrict__ qo, unsigned short* __restrict__ ko,
    unsigned short* __restrict__ vo) {
  __shared__ unsigned short As[128 * 64];
  __shared__ unsigned short Bs[128 * 64];
  int tid = threadIdx.x;
  int lane = tid & 63, wave = tid >> 6;
  int wr = wave >> 1, wc = wave & 1;
  int l15 = lane & 15, lg = lane >> 4;
  size_t bm = (size_t)blockIdx.x * 128, bn = (size_t)blockIdx.y * 128;
  f32x4 acc[4][4] = {};
  for (int kt = 0; kt < K; kt += 64) {
#pragma unroll
    for (int i = 0; i < 4; ++i) {
      int c = tid + i * 256;
      int row = c >> 3, cc = c & 7;
      int4 va = *reinterpret_cast<const int4*>(A + (bm + row) * K + kt + cc * 8);
      *reinterpret_cast<int4*>(&As[row * 64 + ((cc * 8) ^ ((row & 7) << 3))]) = va;
      int4 vb = *reinterpret_cast<const int4*>(BT + (bn + row) * K + kt + cc * 8);
      *reinterpret_cast<int4*>(&Bs[row * 64 + ((cc * 8) ^ ((row & 7) << 3))]) = vb;
    }
    __syncthreads();
#pragma unroll
    for (int kk = 0; kk < 64; kk += 32) {
      int kb = kk + lg * 8;
      short8 af[4], bfr[4];
#pragma unroll
      for (int m = 0; m < 4; ++m) {
        int row = wr * 64 + m * 16 + l15;
        af[m] = *reinterpret_cast<const short8*>(&As[row * 64 + (kb ^ ((row & 7) << 3))]);
      }
#pragma unroll
      for (int n = 0; n < 4; ++n) {
        int row = wc * 64 + n * 16 + l15;
        bfr[n] = *reinterpret_cast<const short8*>(&Bs[row * 64 + (kb ^ ((row & 7) << 3))]);
      }
#pragma unroll
      for (int m = 0; m < 4; ++m)
#pragma unroll
        for (int n = 0; n < 4; ++n)
          acc[m][n] = __builtin_amdgcn_mfma_f32_16x16x32_bf16(af[m], bfr[n], acc[m][n], 0, 0, 0);
    }
    __syncthreads();
  }
#pragma unroll
  for (int m = 0; m < 4; ++m) {
#pragma unroll
    for (int n = 0; n < 4; ++n) {
#pragma unroll
      for (int r = 0; r < 4; ++r) {
        int row = (int)bm + wr * 64 + m * 16 + lg * 4 + r;
        int col = (int)bn + wc * 64 + n * 16 + l15;
        float val = acc[m][n][r];
        if constexpr (EPI == 0) {
          int proj = col / CDIM, rem = col % CDIM;
          int h = rem >> 6, d = rem & 63;
          int b = row >> 11, t = row & (TSEQ - 1);
          size_t idx = (((size_t)(b * NHEAD + h)) * TSEQ + t) * DHEAD + d;
          unsigned short bv = f2bf(val);
          if (proj == 0) qo[idx] = bv;
          else if (proj == 1) ko[idx] = bv;
          else vo[idx] = bv;
        } else if constexpr (EPI == 1) {
          size_t idx = (size_t)row * CDIM + col;
          outf[idx] = val + bias[col] + aux[idx];
        } else if constexpr (EPI == 2) {
          size_t idx = (size_t)row * FDIM + col;
          outb[idx] = f2bf(fmaxf(val + bias[col], 0.f));
        } else {
          size_t idx = (size_t)row * CDIM + col;
          outf[idx] = aux[idx] + fmaxf(val + bias[col], 0.f);
        }
      }
    }
  }
}

// ------------- causal flash attention v2 -------------
// 1 wave = 16 q rows, KV tile = 64, K register-prefetch, MFMA ones-column row-sum,
// heavy-first balanced dispatch.
__global__ __launch_bounds__(256, 3) void attn_kernel(
    const unsigned short* __restrict__ Q, const unsigned short* __restrict__ Kd,
    const unsigned short* __restrict__ VT, unsigned short* __restrict__ O) {
  __shared__ unsigned short plds[4][16 * 72];  // per-wave P buffer, pitch 144B
  int wave = threadIdx.x >> 6, lane = threadIdx.x & 63;
  int bh = blockIdx.x % BH;                  // all heads' heavy tiles dispatch first
  int posw = (blockIdx.x / BH) * 4 + wave;   // 0..127
  int qbase = (127 - posw) * 16;             // heavy-first
  int l15 = lane & 15, lg = lane >> 4;
  const unsigned short* qp = Q + (size_t)bh * TSEQ * DHEAD;
  const unsigned short* kp = Kd + (size_t)bh * TSEQ * DHEAD;
  const unsigned short* vp = VT + (size_t)bh * DHEAD * TSEQ;
  unsigned short* pw = plds[wave];

  short8 qf[2];
#pragma unroll
  for (int kk = 0; kk < 2; ++kk)
    qf[kk] = *reinterpret_cast<const short8*>(qp + (size_t)(qbase + l15) * DHEAD + kk * 32 + lg * 8);

  // ones B-fragment: output col 0 accumulates row-sums of P (rescales like O)
  short8 ones;
  {
    unsigned short ov = (l15 == 0) ? (unsigned short)0x3F80 : (unsigned short)0;
#pragma unroll
    for (int j = 0; j < 8; ++j) ones[j] = (short)ov;
  }

  f32x4 oacc[5] = {};  // [0..3] = O d-tiles, [4] = row-sum column
  float mrun[4];
#pragma unroll
  for (int r = 0; r < 4; ++r) mrun[r] = -1e30f;
  const float SCE = 0.03608439182435161f * 1.4426950408889634f;  // 768^-0.5 * log2(e)

  const int send = qbase + 16;

  auto ldk = [&](short8 (&kb)[4][2], int s0) {
#pragma unroll
    for (int st = 0; st < 4; ++st)
#pragma unroll
      for (int kk = 0; kk < 2; ++kk)
        kb[st][kk] = *reinterpret_cast<const short8*>(
            kp + (size_t)(s0 + st * 16 + l15) * DHEAD + kk * 32 + lg * 8);
  };

  auto body = [&](short8 (&kc)[4][2], short8 (&kn)[4][2], int s0) {
    f32x4 sacc[4] = {};
#pragma unroll
    for (int st = 0; st < 4; ++st)
#pragma unroll
      for (int kk = 0; kk < 2; ++kk)
        sacc[st] = __builtin_amdgcn_mfma_f32_16x16x32_bf16(qf[kk], kc[st][kk], sacc[st], 0, 0, 0);
    if (s0 + 64 < send) ldk(kn, s0 + 64);  // prefetch next K tile (hidden under softmax+PV)
#pragma unroll
    for (int r = 0; r < 4; ++r) {
      int qrow = qbase + lg * 4 + r;
      float e[4];
#pragma unroll
      for (int st = 0; st < 4; ++st)
        e[st] = (s0 + st * 16 + l15 > qrow) ? -1e30f : sacc[st][r] * SCE;
      float mr = fmaxf(fmaxf(e[0], e[1]), fmaxf(e[2], e[3]));
#pragma unroll
      for (int msk = 1; msk < 16; msk <<= 1) mr = fmaxf(mr, __shfl_xor(mr, msk));
      float mnew = fmaxf(mrun[r], mr);
      float alpha = exp2f(mrun[r] - mnew);
      mrun[r] = mnew;
#pragma unroll
      for (int st = 0; st < 4; ++st)
        pw[(lg * 4 + r) * 72 + st * 16 + l15] = f2bf(exp2f(e[st] - mnew));
#pragma unroll
      for (int n = 0; n < 5; ++n) oacc[n][r] *= alpha;
    }
    short8 pa0 = *reinterpret_cast<const short8*>(pw + l15 * 72 + lg * 8);
    short8 pa1 = *reinterpret_cast<const short8*>(pw + l15 * 72 + 32 + lg * 8);
#pragma unroll
    for (int n = 0; n < 4; ++n) {
      short8 vf0 = *reinterpret_cast<const short8*>(
          vp + (size_t)(n * 16 + l15) * TSEQ + s0 + lg * 8);
      oacc[n] = __builtin_amdgcn_mfma_f32_16x16x32_bf16(pa0, vf0, oacc[n], 0, 0, 0);
      short8 vf1 = *reinterpret_cast<const short8*>(
          vp + (size_t)(n * 16 + l15) * TSEQ + s0 + 32 + lg * 8);
      oacc[n] = __builtin_amdgcn_mfma_f32_16x16x32_bf16(pa1, vf1, oacc[n], 0, 0, 0);
    }
    oacc[4] = __builtin_amdgcn_mfma_f32_16x16x32_bf16(pa0, ones, oacc[4], 0, 0, 0);
    oacc[4] = __builtin_amdgcn_mfma_f32_16x16x32_bf16(pa1, ones, oacc[4], 0, 0, 0);
  };

  short8 kA[4][2], kB[4][2];
  ldk(kA, 0);
  for (int s0 = 0;; s0 += 128) {
    body(kA, kB, s0);
    if (s0 + 64 >= send) break;
    body(kB, kA, s0 + 64);
    if (s0 + 128 >= send) break;
  }

  int b = bh / NHEAD, h = bh % NHEAD;
#pragma unroll
  for (int r = 0; r < 4; ++r) {
    float lsum = __shfl(oacc[4][r], lane & 48);  // col 0 of ones-tile, same lg group
    float inv = 1.f / lsum;
    int row = qbase + lg * 4 + r;
#pragma unroll
    for (int n = 0; n < 4; ++n)
      O[(size_t)(b * TSEQ + row) * CDIM + h * DHEAD + n * 16 + l15] = f2bf(oacc[n][r] * inv);
  }
}

extern "C" void kernel_launch(void* const* d_in, const int* in_sizes, int n_in,
                              void* d_out, int out_size, void* d_ws, size_t ws_size,
                              hipStream_t stream) {
  const float* x    = (const float*)d_in[0];
  const float* Wq   = (const float*)d_in[1];
  const float* Wk   = (const float*)d_in[2];
  const float* Wv   = (const float*)d_in[3];
  const float* Wp   = (const float*)d_in[4];
  const float* bp   = (const float*)d_in[5];
  const float* W1   = (const float*)d_in[6];
  const float* b1   = (const float*)d_in[7];
  const float* W2   = (const float*)d_in[8];
  const float* b2   = (const float*)d_in[9];
  const float* ln1g = (const float*)d_in[10];
  const float* ln1b = (const float*)d_in[11];
  const float* ln2g = (const float*)d_in[12];
  const float* ln2b = (const float*)d_in[13];
  float* out = (float*)d_out;

  char* ws = (char*)d_ws;
  auto alloc = [&](size_t bytes) {
    char* p = ws;
    ws += (bytes + 255) & ~(size_t)255;
    return p;
  };
  unsigned short* h1    = (unsigned short*)alloc((size_t)MROWS * CDIM * 2);
  unsigned short* WqkvT = (unsigned short*)alloc((size_t)3 * CDIM * CDIM * 2);
  unsigned short* WpT   = (unsigned short*)alloc((size_t)CDIM * CDIM * 2);
  unsigned short* W1T   = (unsigned short*)alloc((size_t)FDIM * CDIM * 2);
  unsigned short* W2T   = (unsigned short*)alloc((size_t)CDIM * FDIM * 2);
  unsigned short* Qb    = (unsigned short*)alloc((size_t)BH * TSEQ * DHEAD * 2);
  unsigned short* Kb    = (unsigned short*)alloc((size_t)BH * TSEQ * DHEAD * 2);
  unsigned short* Vb    = (unsigned short*)alloc((size_t)BH * TSEQ * DHEAD * 2);
  unsigned short* VTb   = (unsigned short*)alloc((size_t)BH * TSEQ * DHEAD * 2);
  unsigned short* AO    = (unsigned short*)alloc((size_t)MROWS * CDIM * 2);
  float*          x1    = (float*)alloc((size_t)MROWS * CDIM * 4);
  unsigned short* h2    = (unsigned short*)alloc((size_t)MROWS * CDIM * 2);
  unsigned short* a1    = (unsigned short*)alloc((size_t)MROWS * FDIM * 2);

  // weight packs (bf16, B^T layout)
  qkv_pack<<<dim3(24, 2, 36), 256, 0, stream>>>(Wq, Wk, Wv, WqkvT);
  transpose_pack<<<dim3(24, 24), 256, 0, stream>>>(Wp, WpT, CDIM, CDIM);
  transpose_pack<<<dim3(96, 24), 256, 0, stream>>>(W1, W1T, CDIM, FDIM);
  transpose_pack<<<dim3(24, 96), 256, 0, stream>>>(W2, W2T, FDIM, CDIM);

  // LN1 -> h1
  ln_kernel<<<4096, 256, 0, stream>>>(x, ln1g, ln1b, h1);
  // QKV projection
  gemm_bt<0><<<dim3(32, 18), 256, 0, stream>>>(h1, WqkvT, MROWS, 3 * CDIM, CDIM,
                                               nullptr, nullptr, nullptr, nullptr, Qb, Kb, Vb);
  // V -> V^T
  vtrans<<<dim3(64, 2, BH), 256, 0, stream>>>(Vb, VTb);
  // attention
  attn_kernel<<<768, 256, 0, stream>>>(Qb, Kb, VTb, AO);
  // output projection + residual -> x1 (fp32)
  gemm_bt<1><<<dim3(32, 6), 256, 0, stream>>>(AO, WpT, MROWS, CDIM, CDIM,
                                              bp, x, x1, nullptr, nullptr, nullptr, nullptr);
  // LN2 -> h2
  ln_kernel<<<4096, 256, 0, stream>>>(x1, ln2g, ln2b, h2);
  // FF1 (+ReLU) -> a1 bf16
  gemm_bt<2><<<dim3(32, 24), 256, 0, stream>>>(h2, W1T, MROWS, FDIM, CDIM,
                                               b1, nullptr, nullptr, a1, nullptr, nullptr, nullptr);
  // FF2 (+ReLU) + residual -> out fp32
  gemm_bt<3><<<dim3(32, 6), 256, 0, stream>>>(a1, W2T, MROWS, CDIM, FDIM,
                                              b2, x1, out, nullptr, nullptr, nullptr, nullptr);
}